// Round 14
// baseline (1825.150 us; speedup 1.0000x reference)
//
#include <hip/hip_runtime.h>
#include <math.h>

#define N_LIT 200000
#define N_CLS 800000
#define NEDGE 2400000
#define NVAR  (N_LIT / 2)

// CSR radix-partition parameters: 200 chunks x 12000 edges = NEDGE exactly; 196 buckets
#define NBLK_S 200
#define CHUNK  12000
#define NBKT   196

typedef __attribute__((ext_vector_type(8))) short bf16x8;
typedef __attribute__((ext_vector_type(4))) float f32x4;

__device__ __forceinline__ float silu_f(float x) { return x / (1.0f + expf(-x)); }

__device__ __forceinline__ float bf2f(unsigned short u) {
    unsigned int x = ((unsigned int)u) << 16;
    return __uint_as_float(x);
}
__device__ __forceinline__ unsigned short f2bf(float f) {
    unsigned int x = __float_as_uint(f);
    unsigned int r = (x + 0x7fffu + ((x >> 16) & 1u)) >> 16;
    return (unsigned short)r;
}

// ---------------------------------------------------------------- diagnostics
__global__ void diag_kernel(float* __restrict__ out, int n, float val) {
    int i = blockIdx.x * blockDim.x + threadIdx.x;
    int stride = gridDim.x * blockDim.x;
    for (; i < n; i += stride) out[i] = val;
}

// ---------------------------------------------------------------- CSR build: radix partition
__global__ __launch_bounds__(256) void csr_hist_kernel(
    const int* __restrict__ key, int shift, int* __restrict__ bh) {
    __shared__ int h[NBKT];
    int b = blockIdx.x, t = threadIdx.x;
    for (int i = t; i < NBKT; i += 256) h[i] = 0;
    __syncthreads();
    int s = b * CHUNK;
    for (int i = t; i < CHUNK; i += 256) atomicAdd(&h[key[s + i] >> shift], 1);
    __syncthreads();
    for (int i = t; i < NBKT; i += 256) bh[b * NBKT + i] = h[i];
}

__global__ __launch_bounds__(256) void csr_offsets_kernel(
    const int* __restrict__ bh, int* __restrict__ off, int* __restrict__ bktbase) {
    __shared__ int sc[256];
    int t = threadIdx.x;
    int sum = 0;
    if (t < NBKT)
        for (int b = 0; b < NBLK_S; ++b) sum += bh[b * NBKT + t];
    int v = sum;
    sc[t] = v; __syncthreads();
    for (int o = 1; o < 256; o <<= 1) {
        int add = (t >= o) ? sc[t - o] : 0; __syncthreads();
        sc[t] += add; __syncthreads();
    }
    int base = sc[t] - v;   // exclusive
    if (t < NBKT) {
        bktbase[t] = base;
        int run = base;
        for (int b = 0; b < NBLK_S; ++b) { off[b * NBKT + t] = run; run += bh[b * NBKT + t]; }
    }
    if (t == 0) bktbase[NBKT] = NEDGE;
}

__global__ __launch_bounds__(256) void csr_scatter_kernel(
    const int* __restrict__ key, const int* __restrict__ val, int shift,
    const int* __restrict__ off, int2* __restrict__ tmp) {
    __shared__ int cur[NBKT];
    int b = blockIdx.x, t = threadIdx.x;
    for (int i = t; i < NBKT; i += 256) cur[i] = off[b * NBKT + i];
    __syncthreads();
    int s = b * CHUNK;
    for (int i = t; i < CHUNK; i += 256) {
        int k = key[s + i], v = val[s + i];
        int p = atomicAdd(&cur[k >> shift], 1);
        tmp[p] = make_int2(k, v);
    }
}

__global__ __launch_bounds__(256) void csr_build_kernel(
    const int2* __restrict__ tmp, const int* __restrict__ bktbase, int rows_per_bkt,
    int nrows, int* __restrict__ row_ptr, float* __restrict__ inv, int* __restrict__ adj) {
    __shared__ int hist[4096];
    __shared__ int part[256];
    int k = blockIdx.x, t = threadIdx.x;
    int rowbase = k * rows_per_bkt;
    for (int i = t; i < rows_per_bkt; i += 256) hist[i] = 0;
    __syncthreads();
    int e0 = bktbase[k], e1 = bktbase[k + 1];
    for (int e = e0 + t; e < e1; e += 256) atomicAdd(&hist[tmp[e].x - rowbase], 1);
    __syncthreads();
    int per = rows_per_bkt >> 8;   // 16 (cls) or 4 (lit)
    int base_i = t * per;
    int vals[16];
    int s = 0;
    for (int i = 0; i < per; ++i) { vals[i] = hist[base_i + i]; s += vals[i]; }
    int v = s;
    part[t] = v; __syncthreads();
    for (int o = 1; o < 256; o <<= 1) {
        int add = (t >= o) ? part[t - o] : 0; __syncthreads();
        part[t] += add; __syncthreads();
    }
    int run = part[t] - v;
    for (int i = 0; i < per; ++i) { hist[base_i + i] = run; run += vals[i]; }
    __syncthreads();
    for (int i = t; i < rows_per_bkt; i += 256) {
        int row = rowbase + i;
        if (row < nrows) {
            int ex = hist[i];
            int nx = (i + 1 < rows_per_bkt) ? hist[i + 1] : (e1 - e0);
            row_ptr[row] = e0 + ex;
            int d = nx - ex;
            inv[row] = 1.0f / (float)(d > 0 ? d : 1);
        }
    }
    __syncthreads();
    for (int e = e0 + t; e < e1; e += 256) {
        int2 pr = tmp[e];
        int pos = atomicAdd(&hist[pr.x - rowbase], 1);
        adj[e0 + pos] = pr.y;
    }
}

__global__ void tail_kernel(int* __restrict__ rp_cls, int* __restrict__ rp_lit) {
    if (blockIdx.x == 0 && threadIdx.x == 0) {
        rp_cls[N_CLS] = NEDGE;
        rp_lit[N_LIT] = NEDGE;
    }
}

// ---------------------------------------------------------------- encoder (MFMA 2nd GEMM)
__global__ __launch_bounds__(256, 4) void encoder_kernel(
    const float* __restrict__ x_lit, const float* __restrict__ x_cls,
    const float* __restrict__ w1, const float* __restrict__ b1,
    const float* __restrict__ w2, const float* __restrict__ b2,
    float* __restrict__ h_lit, unsigned short* __restrict__ h_cls) {
    __shared__ float w1s[4 * 64];
    __shared__ float b1s[64], b2s[64];
    __shared__ __align__(16) unsigned short Bp[8 * 64 * 8];
    __shared__ float xt[4][64];
    __shared__ float hs[4][16 * 68];
    int t = threadIdx.x;
    w1s[t] = w1[t];
    if (t < 64) { b1s[t] = b1[t]; b2s[t] = b2[t]; }
    for (int idx = t; idx < 8 * 64 * 8; idx += 256) {
        int i = idx & 7, ln = (idx >> 3) & 63, fid = idx >> 9;
        int ks = fid >> 2, nt = fid & 3;
        Bp[idx] = f2bf(w2[(ks * 32 + ((ln >> 4) << 3) + i) * 64 + nt * 16 + (ln & 15)]);
    }
    __syncthreads();
    int w = t >> 6, lane = t & 63;
    int c = lane & 15, q = lane >> 4;
    bf16x8 Bf[8];
    #pragma unroll
    for (int f = 0; f < 8; ++f) Bf[f] = *(const bf16x8*)&Bp[(f * 64 + lane) * 8];
    float* hw = hs[w];
    int nwaves = gridDim.x * 4;
    int wid = blockIdx.x * 4 + w;
    const int ntiles = (N_LIT + N_CLS) / 16;
    for (int tile = wid; tile < ntiles; tile += nwaves) {
        int row0 = tile * 16;
        const float* xsrc = (row0 < N_LIT) ? x_lit + (size_t)row0 * 4
                                           : x_cls + (size_t)(row0 - N_LIT) * 4;
        xt[w][lane] = xsrc[lane];
        for (int r = 0; r < 16; ++r) {
            float pre = b1s[lane];
            #pragma unroll
            for (int k = 0; k < 4; ++k) pre += xt[w][r * 4 + k] * w1s[k * 64 + lane];
            hw[r * 68 + lane] = silu_f(pre);
        }
        bf16x8 A0, A1;
        const float* ap = &hw[c * 68 + q * 8];
        #pragma unroll
        for (int i = 0; i < 8; ++i) {
            A0[i] = (short)f2bf(ap[i]);
            A1[i] = (short)f2bf(ap[32 + i]);
        }
        f32x4 acc[4];
        #pragma unroll
        for (int nt = 0; nt < 4; ++nt) {
            float bv = b2s[nt * 16 + c];
            acc[nt] = (f32x4){bv, bv, bv, bv};
            acc[nt] = __builtin_amdgcn_mfma_f32_16x16x32_bf16(A0, Bf[nt], acc[nt], 0, 0, 0);
            acc[nt] = __builtin_amdgcn_mfma_f32_16x16x32_bf16(A1, Bf[4 + nt], acc[nt], 0, 0, 0);
        }
        #pragma unroll
        for (int nt = 0; nt < 4; ++nt)
            #pragma unroll
            for (int rg = 0; rg < 4; ++rg)
                hw[(q * 4 + rg) * 68 + nt * 16 + c] = acc[nt][rg];
        if (row0 < N_LIT) {
            for (int r = 0; r < 16; ++r)
                h_lit[(size_t)(row0 + r) * 64 + lane] = hw[r * 68 + lane];
        } else {
            for (int r = 0; r < 16; ++r)
                h_cls[(size_t)(row0 + r - N_LIT) * 64 + lane] = f2bf(hw[r * 68 + lane]);
        }
    }
}

// ---------------------------------------------------------------- X = h_lit @ Wc_bot (MFMA) — layer 0 only
__global__ __launch_bounds__(256, 4) void gemmX_kernel(
    const float* __restrict__ in, const float* __restrict__ W,
    unsigned short* __restrict__ out) {
    __shared__ __align__(16) unsigned short Bp[8 * 64 * 8];
    __shared__ float stage[4][16 * 66];
    int t = threadIdx.x;
    for (int idx = t; idx < 8 * 64 * 8; idx += 256) {
        int i = idx & 7, ln = (idx >> 3) & 63, fid = idx >> 9;
        int ks = fid >> 2, nt = fid & 3;
        Bp[idx] = f2bf(W[(ks * 32 + ((ln >> 4) << 3) + i) * 64 + nt * 16 + (ln & 15)]);
    }
    __syncthreads();
    int w = t >> 6, lane = t & 63;
    int c = lane & 15, q = lane >> 4;
    bf16x8 Bf[8];
    #pragma unroll
    for (int f = 0; f < 8; ++f) Bf[f] = *(const bf16x8*)&Bp[(f * 64 + lane) * 8];
    float* ms = stage[w];
    int nwaves = gridDim.x * 4;
    int wid = blockIdx.x * 4 + w;
    for (int tile = wid; tile < N_LIT / 16; tile += nwaves) {
        int row0 = tile * 16;
        const float* ap = in + (size_t)(row0 + c) * 64 + q * 8;
        bf16x8 A0, A1;
        #pragma unroll
        for (int i = 0; i < 8; ++i) {
            A0[i] = (short)f2bf(ap[i]);
            A1[i] = (short)f2bf(ap[32 + i]);
        }
        f32x4 acc[4];
        #pragma unroll
        for (int nt = 0; nt < 4; ++nt) {
            acc[nt] = (f32x4){0.f, 0.f, 0.f, 0.f};
            acc[nt] = __builtin_amdgcn_mfma_f32_16x16x32_bf16(A0, Bf[nt], acc[nt], 0, 0, 0);
            acc[nt] = __builtin_amdgcn_mfma_f32_16x16x32_bf16(A1, Bf[4 + nt], acc[nt], 0, 0, 0);
        }
        #pragma unroll
        for (int nt = 0; nt < 4; ++nt)
            #pragma unroll
            for (int rg = 0; rg < 4; ++rg)
                ms[(q * 4 + rg) * 66 + nt * 16 + c] = acc[nt][rg];
        for (int r = 0; r < 16; ++r)
            out[(size_t)(row0 + r) * 64 + lane] = f2bf(ms[r * 66 + lane]);
    }
}

// ---------------------------------------------------------------- clause update (R12 config: Bp LDS, 6 blocks/CU)
// S_new[c] = silu((S[c] @ Wc_top + bc) + inv[c] * sum_e X[lit[e]])
// 6 blocks/CU measured optimal: 8 blocks thrashes per-XCD L2 on the X gather
// (R13: FETCH 265->380 MB, net regression).
__global__ __launch_bounds__(256, 6) void cls_update_kernel(
    unsigned short* __restrict__ h_cls, const unsigned short* __restrict__ X,
    const int* __restrict__ rp, const int* __restrict__ lits,
    const float* __restrict__ inv_deg, const float* __restrict__ W,
    const float* __restrict__ b) {
    __shared__ __align__(16) unsigned short Bp[8 * 64 * 8];
    __shared__ float bs[64];
    __shared__ float stage[4][16 * 66];
    __shared__ int rps[4][17];
    __shared__ float invs[4][16];
    int t = threadIdx.x;
    for (int idx = t; idx < 8 * 64 * 8; idx += 256) {
        int i = idx & 7, ln = (idx >> 3) & 63, fid = idx >> 9;
        int ks = fid >> 2, nt = fid & 3;
        Bp[idx] = f2bf(W[(ks * 32 + ((ln >> 4) << 3) + i) * 64 + nt * 16 + (ln & 15)]);
    }
    if (t < 64) bs[t] = b[t];
    __syncthreads();
    int w = t >> 6, lane = t & 63;
    int c = lane & 15, q = lane >> 4;
    bf16x8 Bf[8];
    #pragma unroll
    for (int f = 0; f < 8; ++f) Bf[f] = *(const bf16x8*)&Bp[(f * 64 + lane) * 8];
    float* ms = stage[w];
    int* rpw = rps[w];
    float* ivw = invs[w];
    const unsigned short* Xl = X + lane;
    int nwaves = gridDim.x * 4;
    int wid = blockIdx.x * 4 + w;
    for (int tile = wid; tile < N_CLS / 16; tile += nwaves) {
        int row0 = tile * 16;
        const unsigned short* ap = h_cls + (size_t)(row0 + c) * 64 + q * 8;
        bf16x8 A0 = *(const bf16x8*)(ap);
        bf16x8 A1 = *(const bf16x8*)(ap + 32);
        f32x4 acc[4];
        #pragma unroll
        for (int nt = 0; nt < 4; ++nt) {
            float bv = bs[nt * 16 + c];
            acc[nt] = (f32x4){bv, bv, bv, bv};
            acc[nt] = __builtin_amdgcn_mfma_f32_16x16x32_bf16(A0, Bf[nt], acc[nt], 0, 0, 0);
            acc[nt] = __builtin_amdgcn_mfma_f32_16x16x32_bf16(A1, Bf[4 + nt], acc[nt], 0, 0, 0);
        }
        #pragma unroll
        for (int r2 = 0; r2 < 16; ++r2) ms[r2 * 66 + lane] = 0.f;
        if (lane < 17) rpw[lane] = rp[row0 + lane];
        if (lane < 16) ivw[lane] = inv_deg[row0 + lane];
        int E0 = __builtin_amdgcn_readfirstlane(rpw[0]);
        int E1 = __builtin_amdgcn_readfirstlane(rpw[16]);
        int r = 0;
        int endr = __builtin_amdgcn_readfirstlane(rpw[1]);
        float racc = 0.f;
        for (int base = E0; base < E1; base += 64) {
            int n = E1 - base; if (n > 64) n = 64;
            int myLit = (lane < n) ? lits[base + lane] : 0;
            int i = 0;
            for (; i + 15 < n; i += 16) {
                float v[16];
                #pragma unroll
                for (int k = 0; k < 16; ++k) {
                    int lit = __builtin_amdgcn_readlane(myLit, i + k);
                    v[k] = bf2f(Xl[(size_t)lit * 64]);
                }
                #pragma unroll
                for (int k = 0; k < 16; ++k) {
                    int g = base + i + k;
                    while (g >= endr) {
                        ms[r * 66 + lane] = racc * ivw[r];
                        racc = 0.f; ++r;
                        endr = __builtin_amdgcn_readfirstlane(rpw[r + 1]);
                    }
                    racc += v[k];
                }
            }
            for (; i + 7 < n; i += 8) {
                float v[8];
                #pragma unroll
                for (int k = 0; k < 8; ++k) {
                    int lit = __builtin_amdgcn_readlane(myLit, i + k);
                    v[k] = bf2f(Xl[(size_t)lit * 64]);
                }
                #pragma unroll
                for (int k = 0; k < 8; ++k) {
                    int g = base + i + k;
                    while (g >= endr) {
                        ms[r * 66 + lane] = racc * ivw[r];
                        racc = 0.f; ++r;
                        endr = __builtin_amdgcn_readfirstlane(rpw[r + 1]);
                    }
                    racc += v[k];
                }
            }
            for (; i < n; ++i) {
                int lit = __builtin_amdgcn_readlane(myLit, i);
                float v0 = bf2f(Xl[(size_t)lit * 64]);
                int g = base + i;
                while (g >= endr) {
                    ms[r * 66 + lane] = racc * ivw[r];
                    racc = 0.f; ++r;
                    endr = __builtin_amdgcn_readfirstlane(rpw[r + 1]);
                }
                racc += v0;
            }
        }
        if (E1 > E0) ms[r * 66 + lane] = racc * ivw[r];
        #pragma unroll
        for (int nt = 0; nt < 4; ++nt)
            #pragma unroll
            for (int rg = 0; rg < 4; ++rg)
                ms[(q * 4 + rg) * 66 + nt * 16 + c] += acc[nt][rg];
        for (int rr = 0; rr < 16; ++rr)
            h_cls[(size_t)(row0 + rr) * 64 + lane] = f2bf(silu_f(ms[rr * 66 + lane]));
    }
}

// ---------------------------------------------------------------- lit-side gather (scalarized indices, 8-way MLP)
__global__ __launch_bounds__(256, 8) void gather_lit_kernel(
    const unsigned short* __restrict__ S, const int* __restrict__ rp,
    const int* __restrict__ clss, const float* __restrict__ inv_deg,
    unsigned short* __restrict__ m_out) {
    int nw = (gridDim.x * blockDim.x) >> 6;
    int wid = (blockIdx.x * blockDim.x + threadIdx.x) >> 6;
    int lane = threadIdx.x & 63;
    const unsigned short* Sl = S + lane;
    for (int row = wid; row < N_LIT; row += nw) {
        int e0 = __builtin_amdgcn_readfirstlane(rp[row]);
        int e1 = __builtin_amdgcn_readfirstlane(rp[row + 1]);
        float g0 = 0.f, g1 = 0.f, g2 = 0.f, g3 = 0.f;
        float g4 = 0.f, g5 = 0.f, g6 = 0.f, g7 = 0.f;
        for (int base = e0; base < e1; base += 64) {
            int n = e1 - base; if (n > 64) n = 64;
            int myCls = (lane < n) ? clss[base + lane] : 0;
            int i = 0;
            for (; i + 7 < n; i += 8) {
                int c0 = __builtin_amdgcn_readlane(myCls, i);
                int c1 = __builtin_amdgcn_readlane(myCls, i + 1);
                int c2 = __builtin_amdgcn_readlane(myCls, i + 2);
                int c3 = __builtin_amdgcn_readlane(myCls, i + 3);
                int c4 = __builtin_amdgcn_readlane(myCls, i + 4);
                int c5 = __builtin_amdgcn_readlane(myCls, i + 5);
                int c6 = __builtin_amdgcn_readlane(myCls, i + 6);
                int c7 = __builtin_amdgcn_readlane(myCls, i + 7);
                g0 += bf2f(Sl[(size_t)c0 * 64]);
                g1 += bf2f(Sl[(size_t)c1 * 64]);
                g2 += bf2f(Sl[(size_t)c2 * 64]);
                g3 += bf2f(Sl[(size_t)c3 * 64]);
                g4 += bf2f(Sl[(size_t)c4 * 64]);
                g5 += bf2f(Sl[(size_t)c5 * 64]);
                g6 += bf2f(Sl[(size_t)c6 * 64]);
                g7 += bf2f(Sl[(size_t)c7 * 64]);
            }
            for (; i + 3 < n; i += 4) {
                int c0 = __builtin_amdgcn_readlane(myCls, i);
                int c1 = __builtin_amdgcn_readlane(myCls, i + 1);
                int c2 = __builtin_amdgcn_readlane(myCls, i + 2);
                int c3 = __builtin_amdgcn_readlane(myCls, i + 3);
                g0 += bf2f(Sl[(size_t)c0 * 64]);
                g1 += bf2f(Sl[(size_t)c1 * 64]);
                g2 += bf2f(Sl[(size_t)c2 * 64]);
                g3 += bf2f(Sl[(size_t)c3 * 64]);
            }
            for (; i < n; ++i) {
                int c0 = __builtin_amdgcn_readlane(myCls, i);
                g0 += bf2f(Sl[(size_t)c0 * 64]);
            }
        }
        m_out[(size_t)row * 64 + lane] =
            f2bf((((g0 + g1) + (g2 + g3)) + ((g4 + g5) + (g6 + g7))) * inv_deg[row]);
    }
}

// ---------------------------------------------------------------- literal update (MFMA; B-frags direct from global; Bp2 in LDS)
// h[row] = silu([h[row], m[row], h[row^1]] @ W + b); if Wc_next: X[row] = h_new @ Wc_next
// Streaming-access kernel: higher occupancy (5 blocks/CU) is thrash-safe.
__global__ __launch_bounds__(256, 5) void lit_update_kernel(
    float* __restrict__ h, const unsigned short* __restrict__ m,
    const float* __restrict__ W, const float* __restrict__ b,
    const float* __restrict__ Wc_next, unsigned short* __restrict__ Xout) {
    __shared__ __align__(16) unsigned short Bp2[8 * 64 * 8];   // 8 KB (next-layer Wc_bot)
    __shared__ float bs[64];
    __shared__ float stage[4][16 * 66];
    int t = threadIdx.x;
    if (Wc_next) {
        for (int idx = t; idx < 8 * 64 * 8; idx += 256) {
            int i = idx & 7, ln = (idx >> 3) & 63, fid = idx >> 9;
            int ks = fid >> 2, nt = fid & 3;
            Bp2[idx] = f2bf(Wc_next[(ks * 32 + ((ln >> 4) << 3) + i) * 64 + nt * 16 + (ln & 15)]);
        }
    }
    if (t < 64) bs[t] = b[t];
    __syncthreads();
    int w = t >> 6, lane = t & 63;
    int c = lane & 15, q = lane >> 4;
    bf16x8 Bf[24];
    #pragma unroll
    for (int f = 0; f < 24; ++f) {
        int ks = f >> 2, nt = f & 3;
        #pragma unroll
        for (int i = 0; i < 8; ++i)
            Bf[f][i] = (short)f2bf(W[(ks * 32 + q * 8 + i) * 64 + nt * 16 + c]);
    }
    float* ms = stage[w];
    int nwaves = gridDim.x * 4;
    int wid = blockIdx.x * 4 + w;
    for (int tile = wid; tile < N_LIT / 16; tile += nwaves) {
        int row0 = tile * 16;
        bf16x8 A[6];
        const float* hp = h + (size_t)(row0 + c) * 64 + q * 8;
        const float* hf = h + (size_t)((row0 + c) ^ 1) * 64 + q * 8;
        const unsigned short* mp = m + (size_t)(row0 + c) * 64 + q * 8;
        #pragma unroll
        for (int i = 0; i < 8; ++i) {
            A[0][i] = (short)f2bf(hp[i]);
            A[1][i] = (short)f2bf(hp[32 + i]);
            A[4][i] = (short)f2bf(hf[i]);
            A[5][i] = (short)f2bf(hf[32 + i]);
        }
        A[2] = *(const bf16x8*)(mp);
        A[3] = *(const bf16x8*)(mp + 32);
        f32x4 acc[4];
        #pragma unroll
        for (int nt = 0; nt < 4; ++nt) {
            float bv = bs[nt * 16 + c];
            acc[nt] = (f32x4){bv, bv, bv, bv};
            #pragma unroll
            for (int ks = 0; ks < 6; ++ks)
                acc[nt] = __builtin_amdgcn_mfma_f32_16x16x32_bf16(A[ks], Bf[ks * 4 + nt], acc[nt], 0, 0, 0);
        }
        #pragma unroll
        for (int nt = 0; nt < 4; ++nt)
            #pragma unroll
            for (int rg = 0; rg < 4; ++rg)
                ms[(q * 4 + rg) * 66 + nt * 16 + c] = silu_f(acc[nt][rg]);
        for (int r = 0; r < 16; ++r)
            h[(size_t)(row0 + r) * 64 + lane] = ms[r * 66 + lane];
        if (Wc_next) {
            bf16x8 NA0, NA1;
            const float* np = &ms[c * 66 + q * 8];
            #pragma unroll
            for (int i = 0; i < 8; ++i) {
                NA0[i] = (short)f2bf(np[i]);
                NA1[i] = (short)f2bf(np[32 + i]);
            }
            f32x4 xacc[4];
            #pragma unroll
            for (int nt = 0; nt < 4; ++nt) {
                xacc[nt] = (f32x4){0.f, 0.f, 0.f, 0.f};
                bf16x8 B0 = *(const bf16x8*)&Bp2[(nt * 64 + lane) * 8];
                xacc[nt] = __builtin_amdgcn_mfma_f32_16x16x32_bf16(NA0, B0, xacc[nt], 0, 0, 0);
                bf16x8 B1 = *(const bf16x8*)&Bp2[((4 + nt) * 64 + lane) * 8];
                xacc[nt] = __builtin_amdgcn_mfma_f32_16x16x32_bf16(NA1, B1, xacc[nt], 0, 0, 0);
            }
            #pragma unroll
            for (int nt = 0; nt < 4; ++nt)
                #pragma unroll
                for (int rg = 0; rg < 4; ++rg)
                    ms[(q * 4 + rg) * 66 + nt * 16 + c] = xacc[nt][rg];
            for (int r = 0; r < 16; ++r)
                Xout[(size_t)(row0 + r) * 64 + lane] = f2bf(ms[r * 66 + lane]);
        }
    }
}

// ---------------------------------------------------------------- readout stage 1 (fp32 VALU -> bf16 hid)
__global__ __launch_bounds__(256) void var_hidden_kernel(
    const float* __restrict__ h_var, const float* __restrict__ W,
    const float* __restrict__ b, int colofs, unsigned short* __restrict__ hid) {
    __shared__ float Ws[128 * 64];
    __shared__ float bs[64];
    __shared__ float rs[16 * 128];
    int t = threadIdx.x;
    for (int i = t; i < 128 * 64; i += 256) {
        int k = i >> 6, j = i & 63;
        Ws[i] = W[k * 128 + colofs + j];
    }
    if (t < 64) bs[t] = b[colofs + t];
    __syncthreads();
    const int ntiles = NVAR / 16;
    int w = t >> 6, j = t & 63;
    for (int tile = blockIdx.x; tile < ntiles; tile += gridDim.x) {
        int row0 = tile * 16;
        for (int i = t; i < 2048; i += 256) rs[i] = h_var[(size_t)row0 * 128 + i];
        __syncthreads();
        float acc0 = bs[j], acc1 = bs[j], acc2 = bs[j], acc3 = bs[j];
        const float* r0 = &rs[(w * 4 + 0) * 128];
        const float* r1 = &rs[(w * 4 + 1) * 128];
        const float* r2 = &rs[(w * 4 + 2) * 128];
        const float* r3 = &rs[(w * 4 + 3) * 128];
        #pragma unroll 4
        for (int k = 0; k < 128; k += 4) {
            float w0 = Ws[k * 64 + j], w1v = Ws[(k + 1) * 64 + j];
            float w2v = Ws[(k + 2) * 64 + j], w3v = Ws[(k + 3) * 64 + j];
            float4 a;
            a = *(const float4*)(r0 + k); acc0 += a.x * w0 + a.y * w1v + a.z * w2v + a.w * w3v;
            a = *(const float4*)(r1 + k); acc1 += a.x * w0 + a.y * w1v + a.z * w2v + a.w * w3v;
            a = *(const float4*)(r2 + k); acc2 += a.x * w0 + a.y * w1v + a.z * w2v + a.w * w3v;
            a = *(const float4*)(r3 + k); acc3 += a.x * w0 + a.y * w1v + a.z * w2v + a.w * w3v;
        }
        int row = row0 + w * 4;
        hid[(size_t)(row + 0) * 128 + colofs + j] = f2bf(silu_f(acc0));
        hid[(size_t)(row + 1) * 128 + colofs + j] = f2bf(silu_f(acc1));
        hid[(size_t)(row + 2) * 128 + colofs + j] = f2bf(silu_f(acc2));
        hid[(size_t)(row + 3) * 128 + colofs + j] = f2bf(silu_f(acc3));
        __syncthreads();
    }
}

// ---------------------------------------------------------------- readout stage 2
__global__ __launch_bounds__(256) void out2_kernel(
    const unsigned short* __restrict__ hid, const float* __restrict__ w2,
    const float* __restrict__ b2, float* __restrict__ out) {
    int nw = (gridDim.x * blockDim.x) >> 6;
    int wid = (blockIdx.x * blockDim.x + threadIdx.x) >> 6;
    int lane = threadIdx.x & 63;
    float w00 = w2[lane * 2 + 0], w01 = w2[lane * 2 + 1];
    float w10 = w2[(lane + 64) * 2 + 0], w11 = w2[(lane + 64) * 2 + 1];
    for (int row = wid; row < NVAR; row += nw) {
        float h0 = bf2f(hid[(size_t)row * 128 + lane]);
        float h1 = bf2f(hid[(size_t)row * 128 + 64 + lane]);
        float p0 = h0 * w00 + h1 * w10;
        float p1 = h0 * w01 + h1 * w11;
        #pragma unroll
        for (int off = 32; off > 0; off >>= 1) {
            p0 += __shfl_down(p0, off);
            p1 += __shfl_down(p1, off);
        }
        if (lane == 0) {
            out[(size_t)row * 2 + 0] = p0 + b2[0];
            out[(size_t)row * 2 + 1] = p1 + b2[1];
        }
    }
}

// ---------------------------------------------------------------- launch
extern "C" void kernel_launch(void* const* d_in, const int* in_sizes, int n_in,
                              void* d_out, int out_size, void* d_ws, size_t ws_size,
                              hipStream_t stream) {
    const float* x_lit  = (const float*)d_in[0];
    const float* x_cls  = (const float*)d_in[1];
    const int* edge_lit = (const int*)d_in[2];
    const int* edge_cls = (const int*)d_in[3];
    const float* enc_w1 = (const float*)d_in[4];
    const float* enc_b1 = (const float*)d_in[5];
    const float* enc_w2 = (const float*)d_in[6];
    const float* enc_b2 = (const float*)d_in[7];
    const float* Wc     = (const float*)d_in[8];    // [4][128][64]
    const float* bc     = (const float*)d_in[9];
    const float* Wl     = (const float*)d_in[10];   // [4][192][64]
    const float* bl     = (const float*)d_in[11];
    const float* out_w1 = (const float*)d_in[12];   // [128][128]
    const float* out_b1 = (const float*)d_in[13];
    const float* out_w2 = (const float*)d_in[14];   // [128][2]
    const float* out_b2 = (const float*)d_in[15];
    float* y = (float*)d_out;

    // ---- workspace carve (~208 MB) ----
    const size_t SZ_HLIT = (size_t)N_LIT * 64;
    const size_t SZ_HCLS = (size_t)N_CLS * 64;
    char* p = (char*)d_ws;
    auto take = [&](size_t bytes) -> char* {
        char* r = p; p += (bytes + 255) & ~(size_t)255; return r;
    };
    float*          h_lit      = (float*)take(SZ_HLIT * 4);
    unsigned short* h_cls      = (unsigned short*)take(SZ_HCLS * 2);
    unsigned short* X          = (unsigned short*)take(SZ_HLIT * 2);
    float*          inv_cls    = (float*)take((size_t)N_CLS * 4);
    float*          inv_lit    = (float*)take((size_t)N_LIT * 4);
    int*            row_ptr_cls= (int*)take((size_t)(N_CLS + 1) * 4);
    int*            row_ptr_lit= (int*)take((size_t)(N_LIT + 1) * 4);
    int*            lit_by_cls = (int*)take((size_t)NEDGE * 4);
    int*            cls_by_lit = (int*)take((size_t)NEDGE * 4);
    int*            bh         = (int*)take((size_t)NBLK_S * NBKT * 4);
    int*            off        = (int*)take((size_t)NBLK_S * NBKT * 4);
    int*            bktbase    = (int*)take((size_t)(NBKT + 1) * 4);
    size_t need = (size_t)(p - (char*)d_ws);

    // pair buffer aliases h_lit (dead until encoder): 19.2 MB <= 51.2 MB
    int2* tmp_pairs = (int2*)h_lit;

    dim3 B(256);

    if (ws_size < need) {
        float mb = (float)((double)ws_size / (1024.0 * 1024.0));
        diag_kernel<<<256, B, 0, stream>>>(y, out_size, mb);
        return;
    }

    // ---- CSR build (radix partition) ----
    csr_hist_kernel<<<NBLK_S, B, 0, stream>>>(edge_cls, 12, bh);
    csr_offsets_kernel<<<1, B, 0, stream>>>(bh, off, bktbase);
    csr_scatter_kernel<<<NBLK_S, B, 0, stream>>>(edge_cls, edge_lit, 12, off, tmp_pairs);
    csr_build_kernel<<<NBKT, B, 0, stream>>>(tmp_pairs, bktbase, 4096, N_CLS,
                                             row_ptr_cls, inv_cls, lit_by_cls);
    csr_hist_kernel<<<NBLK_S, B, 0, stream>>>(edge_lit, 10, bh);
    csr_offsets_kernel<<<1, B, 0, stream>>>(bh, off, bktbase);
    csr_scatter_kernel<<<NBLK_S, B, 0, stream>>>(edge_lit, edge_cls, 10, off, tmp_pairs);
    csr_build_kernel<<<NBKT, B, 0, stream>>>(tmp_pairs, bktbase, 1024, N_LIT,
                                             row_ptr_lit, inv_lit, cls_by_lit);
    tail_kernel<<<1, 64, 0, stream>>>(row_ptr_cls, row_ptr_lit);

    // ---- encoder (overwrites tmp_pairs alias region) ----
    encoder_kernel<<<2048, B, 0, stream>>>(x_lit, x_cls, enc_w1, enc_b1, enc_w2, enc_b2,
                                           h_lit, h_cls);

    // layer-0 X; layers 1..3 get X from lit_update's fused epilogue
    gemmX_kernel<<<1024, B, 0, stream>>>(h_lit, Wc + 64 * 64, X);

    for (int l = 0; l < 4; ++l) {
        const float* Wl_l = Wl + (size_t)l * 192 * 64;
        const float* Wc_next = (l < 3) ? (Wc + (size_t)(l + 1) * 128 * 64 + 64 * 64) : nullptr;
        cls_update_kernel<<<2048, B, 0, stream>>>(h_cls, X, row_ptr_cls, lit_by_cls,
                                                  inv_cls, Wc + (size_t)l * 128 * 64,
                                                  bc + l * 64);
        gather_lit_kernel<<<4096, B, 0, stream>>>(h_cls, row_ptr_lit, cls_by_lit,
                                                  inv_lit, X);
        lit_update_kernel<<<1024, B, 0, stream>>>(h_lit, X, Wl_l, bl + l * 64,
                                                  Wc_next, X);
    }

    // ---- readout ----
    var_hidden_kernel<<<4096, B, 0, stream>>>(h_lit, out_w1, out_b1, 0, X);
    var_hidden_kernel<<<4096, B, 0, stream>>>(h_lit, out_w1, out_b1, 64, X);
    out2_kernel<<<2048, B, 0, stream>>>(X, out_w2, out_b2, y);
}

// Round 15
// 1582.871 us; speedup vs baseline: 1.1531x; 1.1531x over previous
//
#include <hip/hip_runtime.h>
#include <math.h>

#define N_LIT 200000
#define N_CLS 800000
#define NEDGE 2400000
#define NVAR  (N_LIT / 2)

// CSR radix-partition parameters: 200 chunks x 12000 edges = NEDGE exactly; 196 buckets
#define NBLK_S 200
#define CHUNK  12000
#define NBKT   196

typedef __attribute__((ext_vector_type(8))) short bf16x8;
typedef __attribute__((ext_vector_type(4))) float f32x4;

__device__ __forceinline__ float silu_f(float x) { return x / (1.0f + expf(-x)); }

__device__ __forceinline__ float bf2f(unsigned short u) {
    unsigned int x = ((unsigned int)u) << 16;
    return __uint_as_float(x);
}
__device__ __forceinline__ unsigned short f2bf(float f) {
    unsigned int x = __float_as_uint(f);
    unsigned int r = (x + 0x7fffu + ((x >> 16) & 1u)) >> 16;
    return (unsigned short)r;
}

// ---------------------------------------------------------------- diagnostics
__global__ void diag_kernel(float* __restrict__ out, int n, float val) {
    int i = blockIdx.x * blockDim.x + threadIdx.x;
    int stride = gridDim.x * blockDim.x;
    for (; i < n; i += stride) out[i] = val;
}

// ---------------------------------------------------------------- CSR build: radix partition
__global__ __launch_bounds__(256) void csr_hist_kernel(
    const int* __restrict__ key, int shift, int* __restrict__ bh) {
    __shared__ int h[NBKT];
    int b = blockIdx.x, t = threadIdx.x;
    for (int i = t; i < NBKT; i += 256) h[i] = 0;
    __syncthreads();
    int s = b * CHUNK;
    for (int i = t; i < CHUNK; i += 256) atomicAdd(&h[key[s + i] >> shift], 1);
    __syncthreads();
    for (int i = t; i < NBKT; i += 256) bh[b * NBKT + i] = h[i];
}

__global__ __launch_bounds__(256) void csr_offsets_kernel(
    const int* __restrict__ bh, int* __restrict__ off, int* __restrict__ bktbase) {
    __shared__ int sc[256];
    int t = threadIdx.x;
    int sum = 0;
    if (t < NBKT)
        for (int b = 0; b < NBLK_S; ++b) sum += bh[b * NBKT + t];
    int v = sum;
    sc[t] = v; __syncthreads();
    for (int o = 1; o < 256; o <<= 1) {
        int add = (t >= o) ? sc[t - o] : 0; __syncthreads();
        sc[t] += add; __syncthreads();
    }
    int base = sc[t] - v;   // exclusive
    if (t < NBKT) {
        bktbase[t] = base;
        int run = base;
        for (int b = 0; b < NBLK_S; ++b) { off[b * NBKT + t] = run; run += bh[b * NBKT + t]; }
    }
    if (t == 0) bktbase[NBKT] = NEDGE;
}

__global__ __launch_bounds__(256) void csr_scatter_kernel(
    const int* __restrict__ key, const int* __restrict__ val, int shift,
    const int* __restrict__ off, int2* __restrict__ tmp) {
    __shared__ int cur[NBKT];
    int b = blockIdx.x, t = threadIdx.x;
    for (int i = t; i < NBKT; i += 256) cur[i] = off[b * NBKT + i];
    __syncthreads();
    int s = b * CHUNK;
    for (int i = t; i < CHUNK; i += 256) {
        int k = key[s + i], v = val[s + i];
        int p = atomicAdd(&cur[k >> shift], 1);
        tmp[p] = make_int2(k, v);
    }
}

__global__ __launch_bounds__(256) void csr_build_kernel(
    const int2* __restrict__ tmp, const int* __restrict__ bktbase, int rows_per_bkt,
    int nrows, int* __restrict__ row_ptr, float* __restrict__ inv, int* __restrict__ adj) {
    __shared__ int hist[4096];
    __shared__ int part[256];
    int k = blockIdx.x, t = threadIdx.x;
    int rowbase = k * rows_per_bkt;
    for (int i = t; i < rows_per_bkt; i += 256) hist[i] = 0;
    __syncthreads();
    int e0 = bktbase[k], e1 = bktbase[k + 1];
    for (int e = e0 + t; e < e1; e += 256) atomicAdd(&hist[tmp[e].x - rowbase], 1);
    __syncthreads();
    int per = rows_per_bkt >> 8;   // 16 (cls) or 4 (lit)
    int base_i = t * per;
    int vals[16];
    int s = 0;
    for (int i = 0; i < per; ++i) { vals[i] = hist[base_i + i]; s += vals[i]; }
    int v = s;
    part[t] = v; __syncthreads();
    for (int o = 1; o < 256; o <<= 1) {
        int add = (t >= o) ? part[t - o] : 0; __syncthreads();
        part[t] += add; __syncthreads();
    }
    int run = part[t] - v;
    for (int i = 0; i < per; ++i) { hist[base_i + i] = run; run += vals[i]; }
    __syncthreads();
    for (int i = t; i < rows_per_bkt; i += 256) {
        int row = rowbase + i;
        if (row < nrows) {
            int ex = hist[i];
            int nx = (i + 1 < rows_per_bkt) ? hist[i + 1] : (e1 - e0);
            row_ptr[row] = e0 + ex;
            int d = nx - ex;
            inv[row] = 1.0f / (float)(d > 0 ? d : 1);
        }
    }
    __syncthreads();
    for (int e = e0 + t; e < e1; e += 256) {
        int2 pr = tmp[e];
        int pos = atomicAdd(&hist[pr.x - rowbase], 1);
        adj[e0 + pos] = pr.y;
    }
}

__global__ void tail_kernel(int* __restrict__ rp_cls, int* __restrict__ rp_lit) {
    if (blockIdx.x == 0 && threadIdx.x == 0) {
        rp_cls[N_CLS] = NEDGE;
        rp_lit[N_LIT] = NEDGE;
    }
}

// ---------------------------------------------------------------- encoder (MFMA 2nd GEMM)
__global__ __launch_bounds__(256, 4) void encoder_kernel(
    const float* __restrict__ x_lit, const float* __restrict__ x_cls,
    const float* __restrict__ w1, const float* __restrict__ b1,
    const float* __restrict__ w2, const float* __restrict__ b2,
    float* __restrict__ h_lit, unsigned short* __restrict__ h_cls) {
    __shared__ float w1s[4 * 64];
    __shared__ float b1s[64], b2s[64];
    __shared__ __align__(16) unsigned short Bp[8 * 64 * 8];
    __shared__ float xt[4][64];
    __shared__ float hs[4][16 * 68];
    int t = threadIdx.x;
    w1s[t] = w1[t];
    if (t < 64) { b1s[t] = b1[t]; b2s[t] = b2[t]; }
    for (int idx = t; idx < 8 * 64 * 8; idx += 256) {
        int i = idx & 7, ln = (idx >> 3) & 63, fid = idx >> 9;
        int ks = fid >> 2, nt = fid & 3;
        Bp[idx] = f2bf(w2[(ks * 32 + ((ln >> 4) << 3) + i) * 64 + nt * 16 + (ln & 15)]);
    }
    __syncthreads();
    int w = t >> 6, lane = t & 63;
    int c = lane & 15, q = lane >> 4;
    bf16x8 Bf[8];
    #pragma unroll
    for (int f = 0; f < 8; ++f) Bf[f] = *(const bf16x8*)&Bp[(f * 64 + lane) * 8];
    float* hw = hs[w];
    int nwaves = gridDim.x * 4;
    int wid = blockIdx.x * 4 + w;
    const int ntiles = (N_LIT + N_CLS) / 16;
    for (int tile = wid; tile < ntiles; tile += nwaves) {
        int row0 = tile * 16;
        const float* xsrc = (row0 < N_LIT) ? x_lit + (size_t)row0 * 4
                                           : x_cls + (size_t)(row0 - N_LIT) * 4;
        xt[w][lane] = xsrc[lane];
        for (int r = 0; r < 16; ++r) {
            float pre = b1s[lane];
            #pragma unroll
            for (int k = 0; k < 4; ++k) pre += xt[w][r * 4 + k] * w1s[k * 64 + lane];
            hw[r * 68 + lane] = silu_f(pre);
        }
        bf16x8 A0, A1;
        const float* ap = &hw[c * 68 + q * 8];
        #pragma unroll
        for (int i = 0; i < 8; ++i) {
            A0[i] = (short)f2bf(ap[i]);
            A1[i] = (short)f2bf(ap[32 + i]);
        }
        f32x4 acc[4];
        #pragma unroll
        for (int nt = 0; nt < 4; ++nt) {
            float bv = b2s[nt * 16 + c];
            acc[nt] = (f32x4){bv, bv, bv, bv};
            acc[nt] = __builtin_amdgcn_mfma_f32_16x16x32_bf16(A0, Bf[nt], acc[nt], 0, 0, 0);
            acc[nt] = __builtin_amdgcn_mfma_f32_16x16x32_bf16(A1, Bf[4 + nt], acc[nt], 0, 0, 0);
        }
        #pragma unroll
        for (int nt = 0; nt < 4; ++nt)
            #pragma unroll
            for (int rg = 0; rg < 4; ++rg)
                hw[(q * 4 + rg) * 68 + nt * 16 + c] = acc[nt][rg];
        if (row0 < N_LIT) {
            for (int r = 0; r < 16; ++r)
                h_lit[(size_t)(row0 + r) * 64 + lane] = hw[r * 68 + lane];
        } else {
            for (int r = 0; r < 16; ++r)
                h_cls[(size_t)(row0 + r - N_LIT) * 64 + lane] = f2bf(hw[r * 68 + lane]);
        }
    }
}

// ---------------------------------------------------------------- X = h_lit @ Wc_bot (MFMA) — layer 0 only
__global__ __launch_bounds__(256, 4) void gemmX_kernel(
    const float* __restrict__ in, const float* __restrict__ W,
    unsigned short* __restrict__ out) {
    __shared__ __align__(16) unsigned short Bp[8 * 64 * 8];
    __shared__ float stage[4][16 * 66];
    int t = threadIdx.x;
    for (int idx = t; idx < 8 * 64 * 8; idx += 256) {
        int i = idx & 7, ln = (idx >> 3) & 63, fid = idx >> 9;
        int ks = fid >> 2, nt = fid & 3;
        Bp[idx] = f2bf(W[(ks * 32 + ((ln >> 4) << 3) + i) * 64 + nt * 16 + (ln & 15)]);
    }
    __syncthreads();
    int w = t >> 6, lane = t & 63;
    int c = lane & 15, q = lane >> 4;
    bf16x8 Bf[8];
    #pragma unroll
    for (int f = 0; f < 8; ++f) Bf[f] = *(const bf16x8*)&Bp[(f * 64 + lane) * 8];
    float* ms = stage[w];
    int nwaves = gridDim.x * 4;
    int wid = blockIdx.x * 4 + w;
    for (int tile = wid; tile < N_LIT / 16; tile += nwaves) {
        int row0 = tile * 16;
        const float* ap = in + (size_t)(row0 + c) * 64 + q * 8;
        bf16x8 A0, A1;
        #pragma unroll
        for (int i = 0; i < 8; ++i) {
            A0[i] = (short)f2bf(ap[i]);
            A1[i] = (short)f2bf(ap[32 + i]);
        }
        f32x4 acc[4];
        #pragma unroll
        for (int nt = 0; nt < 4; ++nt) {
            acc[nt] = (f32x4){0.f, 0.f, 0.f, 0.f};
            acc[nt] = __builtin_amdgcn_mfma_f32_16x16x32_bf16(A0, Bf[nt], acc[nt], 0, 0, 0);
            acc[nt] = __builtin_amdgcn_mfma_f32_16x16x32_bf16(A1, Bf[4 + nt], acc[nt], 0, 0, 0);
        }
        #pragma unroll
        for (int nt = 0; nt < 4; ++nt)
            #pragma unroll
            for (int rg = 0; rg < 4; ++rg)
                ms[(q * 4 + rg) * 66 + nt * 16 + c] = acc[nt][rg];
        for (int r = 0; r < 16; ++r)
            out[(size_t)(row0 + r) * 64 + lane] = f2bf(ms[r * 66 + lane]);
    }
}

// ---------------------------------------------------------------- clause update (MFMA + scalarized monotone gather; R12 best)
// S_new[c] = silu((S[c] @ Wc_top + bc) + inv[c] * sum_e X[lit[e]])
// Bp LDS staging + 6 blocks/CU: measured optimum (8 blocks thrashes per-XCD L2;
// dropping Bp LDS for direct global loads also regressed via occupancy coupling).
__global__ __launch_bounds__(256, 6) void cls_update_kernel(
    unsigned short* __restrict__ h_cls, const unsigned short* __restrict__ X,
    const int* __restrict__ rp, const int* __restrict__ lits,
    const float* __restrict__ inv_deg, const float* __restrict__ W,
    const float* __restrict__ b) {
    __shared__ __align__(16) unsigned short Bp[8 * 64 * 8];
    __shared__ float bs[64];
    __shared__ float stage[4][16 * 66];
    __shared__ int rps[4][17];
    __shared__ float invs[4][16];
    int t = threadIdx.x;
    for (int idx = t; idx < 8 * 64 * 8; idx += 256) {
        int i = idx & 7, ln = (idx >> 3) & 63, fid = idx >> 9;
        int ks = fid >> 2, nt = fid & 3;
        Bp[idx] = f2bf(W[(ks * 32 + ((ln >> 4) << 3) + i) * 64 + nt * 16 + (ln & 15)]);
    }
    if (t < 64) bs[t] = b[t];
    __syncthreads();
    int w = t >> 6, lane = t & 63;
    int c = lane & 15, q = lane >> 4;
    bf16x8 Bf[8];
    #pragma unroll
    for (int f = 0; f < 8; ++f) Bf[f] = *(const bf16x8*)&Bp[(f * 64 + lane) * 8];
    float* ms = stage[w];
    int* rpw = rps[w];
    float* ivw = invs[w];
    const unsigned short* Xl = X + lane;
    int nwaves = gridDim.x * 4;
    int wid = blockIdx.x * 4 + w;
    for (int tile = wid; tile < N_CLS / 16; tile += nwaves) {
        int row0 = tile * 16;
        const unsigned short* ap = h_cls + (size_t)(row0 + c) * 64 + q * 8;
        bf16x8 A0 = *(const bf16x8*)(ap);
        bf16x8 A1 = *(const bf16x8*)(ap + 32);
        f32x4 acc[4];
        #pragma unroll
        for (int nt = 0; nt < 4; ++nt) {
            float bv = bs[nt * 16 + c];
            acc[nt] = (f32x4){bv, bv, bv, bv};
            acc[nt] = __builtin_amdgcn_mfma_f32_16x16x32_bf16(A0, Bf[nt], acc[nt], 0, 0, 0);
            acc[nt] = __builtin_amdgcn_mfma_f32_16x16x32_bf16(A1, Bf[4 + nt], acc[nt], 0, 0, 0);
        }
        #pragma unroll
        for (int r2 = 0; r2 < 16; ++r2) ms[r2 * 66 + lane] = 0.f;
        if (lane < 17) rpw[lane] = rp[row0 + lane];
        if (lane < 16) ivw[lane] = inv_deg[row0 + lane];
        int E0 = __builtin_amdgcn_readfirstlane(rpw[0]);
        int E1 = __builtin_amdgcn_readfirstlane(rpw[16]);
        int r = 0;
        int endr = __builtin_amdgcn_readfirstlane(rpw[1]);
        float racc = 0.f;
        for (int base = E0; base < E1; base += 64) {
            int n = E1 - base; if (n > 64) n = 64;
            int myLit = (lane < n) ? lits[base + lane] : 0;
            int i = 0;
            for (; i + 15 < n; i += 16) {
                float v[16];
                #pragma unroll
                for (int k = 0; k < 16; ++k) {
                    int lit = __builtin_amdgcn_readlane(myLit, i + k);
                    v[k] = bf2f(Xl[(size_t)lit * 64]);
                }
                #pragma unroll
                for (int k = 0; k < 16; ++k) {
                    int g = base + i + k;
                    while (g >= endr) {
                        ms[r * 66 + lane] = racc * ivw[r];
                        racc = 0.f; ++r;
                        endr = __builtin_amdgcn_readfirstlane(rpw[r + 1]);
                    }
                    racc += v[k];
                }
            }
            for (; i + 7 < n; i += 8) {
                float v[8];
                #pragma unroll
                for (int k = 0; k < 8; ++k) {
                    int lit = __builtin_amdgcn_readlane(myLit, i + k);
                    v[k] = bf2f(Xl[(size_t)lit * 64]);
                }
                #pragma unroll
                for (int k = 0; k < 8; ++k) {
                    int g = base + i + k;
                    while (g >= endr) {
                        ms[r * 66 + lane] = racc * ivw[r];
                        racc = 0.f; ++r;
                        endr = __builtin_amdgcn_readfirstlane(rpw[r + 1]);
                    }
                    racc += v[k];
                }
            }
            for (; i < n; ++i) {
                int lit = __builtin_amdgcn_readlane(myLit, i);
                float v0 = bf2f(Xl[(size_t)lit * 64]);
                int g = base + i;
                while (g >= endr) {
                    ms[r * 66 + lane] = racc * ivw[r];
                    racc = 0.f; ++r;
                    endr = __builtin_amdgcn_readfirstlane(rpw[r + 1]);
                }
                racc += v0;
            }
        }
        if (E1 > E0) ms[r * 66 + lane] = racc * ivw[r];
        #pragma unroll
        for (int nt = 0; nt < 4; ++nt)
            #pragma unroll
            for (int rg = 0; rg < 4; ++rg)
                ms[(q * 4 + rg) * 66 + nt * 16 + c] += acc[nt][rg];
        for (int rr = 0; rr < 16; ++rr)
            h_cls[(size_t)(row0 + rr) * 64 + lane] = f2bf(silu_f(ms[rr * 66 + lane]));
    }
}

// ---------------------------------------------------------------- lit-side gather (scalarized indices, 8-way MLP)
__global__ __launch_bounds__(256, 8) void gather_lit_kernel(
    const unsigned short* __restrict__ S, const int* __restrict__ rp,
    const int* __restrict__ clss, const float* __restrict__ inv_deg,
    unsigned short* __restrict__ m_out) {
    int nw = (gridDim.x * blockDim.x) >> 6;
    int wid = (blockIdx.x * blockDim.x + threadIdx.x) >> 6;
    int lane = threadIdx.x & 63;
    const unsigned short* Sl = S + lane;
    for (int row = wid; row < N_LIT; row += nw) {
        int e0 = __builtin_amdgcn_readfirstlane(rp[row]);
        int e1 = __builtin_amdgcn_readfirstlane(rp[row + 1]);
        float g0 = 0.f, g1 = 0.f, g2 = 0.f, g3 = 0.f;
        float g4 = 0.f, g5 = 0.f, g6 = 0.f, g7 = 0.f;
        for (int base = e0; base < e1; base += 64) {
            int n = e1 - base; if (n > 64) n = 64;
            int myCls = (lane < n) ? clss[base + lane] : 0;
            int i = 0;
            for (; i + 7 < n; i += 8) {
                int c0 = __builtin_amdgcn_readlane(myCls, i);
                int c1 = __builtin_amdgcn_readlane(myCls, i + 1);
                int c2 = __builtin_amdgcn_readlane(myCls, i + 2);
                int c3 = __builtin_amdgcn_readlane(myCls, i + 3);
                int c4 = __builtin_amdgcn_readlane(myCls, i + 4);
                int c5 = __builtin_amdgcn_readlane(myCls, i + 5);
                int c6 = __builtin_amdgcn_readlane(myCls, i + 6);
                int c7 = __builtin_amdgcn_readlane(myCls, i + 7);
                g0 += bf2f(Sl[(size_t)c0 * 64]);
                g1 += bf2f(Sl[(size_t)c1 * 64]);
                g2 += bf2f(Sl[(size_t)c2 * 64]);
                g3 += bf2f(Sl[(size_t)c3 * 64]);
                g4 += bf2f(Sl[(size_t)c4 * 64]);
                g5 += bf2f(Sl[(size_t)c5 * 64]);
                g6 += bf2f(Sl[(size_t)c6 * 64]);
                g7 += bf2f(Sl[(size_t)c7 * 64]);
            }
            for (; i + 3 < n; i += 4) {
                int c0 = __builtin_amdgcn_readlane(myCls, i);
                int c1 = __builtin_amdgcn_readlane(myCls, i + 1);
                int c2 = __builtin_amdgcn_readlane(myCls, i + 2);
                int c3 = __builtin_amdgcn_readlane(myCls, i + 3);
                g0 += bf2f(Sl[(size_t)c0 * 64]);
                g1 += bf2f(Sl[(size_t)c1 * 64]);
                g2 += bf2f(Sl[(size_t)c2 * 64]);
                g3 += bf2f(Sl[(size_t)c3 * 64]);
            }
            for (; i < n; ++i) {
                int c0 = __builtin_amdgcn_readlane(myCls, i);
                g0 += bf2f(Sl[(size_t)c0 * 64]);
            }
        }
        m_out[(size_t)row * 64 + lane] =
            f2bf((((g0 + g1) + (g2 + g3)) + ((g4 + g5) + (g6 + g7))) * inv_deg[row]);
    }
}

// ---------------------------------------------------------------- literal update (MFMA, in-place fp32, + fused next-layer X; R12 best)
__global__ __launch_bounds__(256, 3) void lit_update_kernel(
    float* __restrict__ h, const unsigned short* __restrict__ m,
    const float* __restrict__ W, const float* __restrict__ b,
    const float* __restrict__ Wc_next, unsigned short* __restrict__ Xout) {
    __shared__ __align__(16) unsigned short Bp[24 * 64 * 8];
    __shared__ __align__(16) unsigned short Bp2[8 * 64 * 8];
    __shared__ float bs[64];
    __shared__ float stage[4][16 * 66];
    int t = threadIdx.x;
    for (int idx = t; idx < 24 * 64 * 8; idx += 256) {
        int i = idx & 7, ln = (idx >> 3) & 63, fid = idx >> 9;
        int ks = fid >> 2, nt = fid & 3;
        Bp[idx] = f2bf(W[(ks * 32 + ((ln >> 4) << 3) + i) * 64 + nt * 16 + (ln & 15)]);
    }
    if (Wc_next) {
        for (int idx = t; idx < 8 * 64 * 8; idx += 256) {
            int i = idx & 7, ln = (idx >> 3) & 63, fid = idx >> 9;
            int ks = fid >> 2, nt = fid & 3;
            Bp2[idx] = f2bf(Wc_next[(ks * 32 + ((ln >> 4) << 3) + i) * 64 + nt * 16 + (ln & 15)]);
        }
    }
    if (t < 64) bs[t] = b[t];
    __syncthreads();
    int w = t >> 6, lane = t & 63;
    int c = lane & 15, q = lane >> 4;
    bf16x8 Bf[24];
    #pragma unroll
    for (int f = 0; f < 24; ++f) Bf[f] = *(const bf16x8*)&Bp[(f * 64 + lane) * 8];
    float* ms = stage[w];
    int nwaves = gridDim.x * 4;
    int wid = blockIdx.x * 4 + w;
    for (int tile = wid; tile < N_LIT / 16; tile += nwaves) {
        int row0 = tile * 16;
        bf16x8 A[6];
        const float* hp = h + (size_t)(row0 + c) * 64 + q * 8;
        const float* hf = h + (size_t)((row0 + c) ^ 1) * 64 + q * 8;
        const unsigned short* mp = m + (size_t)(row0 + c) * 64 + q * 8;
        #pragma unroll
        for (int i = 0; i < 8; ++i) {
            A[0][i] = (short)f2bf(hp[i]);
            A[1][i] = (short)f2bf(hp[32 + i]);
            A[4][i] = (short)f2bf(hf[i]);
            A[5][i] = (short)f2bf(hf[32 + i]);
        }
        A[2] = *(const bf16x8*)(mp);
        A[3] = *(const bf16x8*)(mp + 32);
        f32x4 acc[4];
        #pragma unroll
        for (int nt = 0; nt < 4; ++nt) {
            float bv = bs[nt * 16 + c];
            acc[nt] = (f32x4){bv, bv, bv, bv};
            #pragma unroll
            for (int ks = 0; ks < 6; ++ks)
                acc[nt] = __builtin_amdgcn_mfma_f32_16x16x32_bf16(A[ks], Bf[ks * 4 + nt], acc[nt], 0, 0, 0);
        }
        #pragma unroll
        for (int nt = 0; nt < 4; ++nt)
            #pragma unroll
            for (int rg = 0; rg < 4; ++rg)
                ms[(q * 4 + rg) * 66 + nt * 16 + c] = silu_f(acc[nt][rg]);
        for (int r = 0; r < 16; ++r)
            h[(size_t)(row0 + r) * 64 + lane] = ms[r * 66 + lane];
        if (Wc_next) {
            bf16x8 NA0, NA1;
            const float* np = &ms[c * 66 + q * 8];
            #pragma unroll
            for (int i = 0; i < 8; ++i) {
                NA0[i] = (short)f2bf(np[i]);
                NA1[i] = (short)f2bf(np[32 + i]);
            }
            f32x4 xacc[4];
            #pragma unroll
            for (int nt = 0; nt < 4; ++nt) {
                xacc[nt] = (f32x4){0.f, 0.f, 0.f, 0.f};
                bf16x8 B0 = *(const bf16x8*)&Bp2[(nt * 64 + lane) * 8];
                xacc[nt] = __builtin_amdgcn_mfma_f32_16x16x32_bf16(NA0, B0, xacc[nt], 0, 0, 0);
                bf16x8 B1 = *(const bf16x8*)&Bp2[((4 + nt) * 64 + lane) * 8];
                xacc[nt] = __builtin_amdgcn_mfma_f32_16x16x32_bf16(NA1, B1, xacc[nt], 0, 0, 0);
            }
            #pragma unroll
            for (int nt = 0; nt < 4; ++nt)
                #pragma unroll
                for (int rg = 0; rg < 4; ++rg)
                    ms[(q * 4 + rg) * 66 + nt * 16 + c] = xacc[nt][rg];
            for (int r = 0; r < 16; ++r)
                Xout[(size_t)(row0 + r) * 64 + lane] = f2bf(ms[r * 66 + lane]);
        }
    }
}

// ---------------------------------------------------------------- readout stage 1 (fp32 VALU -> bf16 hid)
__global__ __launch_bounds__(256) void var_hidden_kernel(
    const float* __restrict__ h_var, const float* __restrict__ W,
    const float* __restrict__ b, int colofs, unsigned short* __restrict__ hid) {
    __shared__ float Ws[128 * 64];
    __shared__ float bs[64];
    __shared__ float rs[16 * 128];
    int t = threadIdx.x;
    for (int i = t; i < 128 * 64; i += 256) {
        int k = i >> 6, j = i & 63;
        Ws[i] = W[k * 128 + colofs + j];
    }
    if (t < 64) bs[t] = b[colofs + t];
    __syncthreads();
    const int ntiles = NVAR / 16;
    int w = t >> 6, j = t & 63;
    for (int tile = blockIdx.x; tile < ntiles; tile += gridDim.x) {
        int row0 = tile * 16;
        for (int i = t; i < 2048; i += 256) rs[i] = h_var[(size_t)row0 * 128 + i];
        __syncthreads();
        float acc0 = bs[j], acc1 = bs[j], acc2 = bs[j], acc3 = bs[j];
        const float* r0 = &rs[(w * 4 + 0) * 128];
        const float* r1 = &rs[(w * 4 + 1) * 128];
        const float* r2 = &rs[(w * 4 + 2) * 128];
        const float* r3 = &rs[(w * 4 + 3) * 128];
        #pragma unroll 4
        for (int k = 0; k < 128; k += 4) {
            float w0 = Ws[k * 64 + j], w1v = Ws[(k + 1) * 64 + j];
            float w2v = Ws[(k + 2) * 64 + j], w3v = Ws[(k + 3) * 64 + j];
            float4 a;
            a = *(const float4*)(r0 + k); acc0 += a.x * w0 + a.y * w1v + a.z * w2v + a.w * w3v;
            a = *(const float4*)(r1 + k); acc1 += a.x * w0 + a.y * w1v + a.z * w2v + a.w * w3v;
            a = *(const float4*)(r2 + k); acc2 += a.x * w0 + a.y * w1v + a.z * w2v + a.w * w3v;
            a = *(const float4*)(r3 + k); acc3 += a.x * w0 + a.y * w1v + a.z * w2v + a.w * w3v;
        }
        int row = row0 + w * 4;
        hid[(size_t)(row + 0) * 128 + colofs + j] = f2bf(silu_f(acc0));
        hid[(size_t)(row + 1) * 128 + colofs + j] = f2bf(silu_f(acc1));
        hid[(size_t)(row + 2) * 128 + colofs + j] = f2bf(silu_f(acc2));
        hid[(size_t)(row + 3) * 128 + colofs + j] = f2bf(silu_f(acc3));
        __syncthreads();
    }
}

// ---------------------------------------------------------------- readout stage 2
__global__ __launch_bounds__(256) void out2_kernel(
    const unsigned short* __restrict__ hid, const float* __restrict__ w2,
    const float* __restrict__ b2, float* __restrict__ out) {
    int nw = (gridDim.x * blockDim.x) >> 6;
    int wid = (blockIdx.x * blockDim.x + threadIdx.x) >> 6;
    int lane = threadIdx.x & 63;
    float w00 = w2[lane * 2 + 0], w01 = w2[lane * 2 + 1];
    float w10 = w2[(lane + 64) * 2 + 0], w11 = w2[(lane + 64) * 2 + 1];
    for (int row = wid; row < NVAR; row += nw) {
        float h0 = bf2f(hid[(size_t)row * 128 + lane]);
        float h1 = bf2f(hid[(size_t)row * 128 + 64 + lane]);
        float p0 = h0 * w00 + h1 * w10;
        float p1 = h0 * w01 + h1 * w11;
        #pragma unroll
        for (int off = 32; off > 0; off >>= 1) {
            p0 += __shfl_down(p0, off);
            p1 += __shfl_down(p1, off);
        }
        if (lane == 0) {
            out[(size_t)row * 2 + 0] = p0 + b2[0];
            out[(size_t)row * 2 + 1] = p1 + b2[1];
        }
    }
}

// ---------------------------------------------------------------- launch
extern "C" void kernel_launch(void* const* d_in, const int* in_sizes, int n_in,
                              void* d_out, int out_size, void* d_ws, size_t ws_size,
                              hipStream_t stream) {
    const float* x_lit  = (const float*)d_in[0];
    const float* x_cls  = (const float*)d_in[1];
    const int* edge_lit = (const int*)d_in[2];
    const int* edge_cls = (const int*)d_in[3];
    const float* enc_w1 = (const float*)d_in[4];
    const float* enc_b1 = (const float*)d_in[5];
    const float* enc_w2 = (const float*)d_in[6];
    const float* enc_b2 = (const float*)d_in[7];
    const float* Wc     = (const float*)d_in[8];    // [4][128][64]
    const float* bc     = (const float*)d_in[9];
    const float* Wl     = (const float*)d_in[10];   // [4][192][64]
    const float* bl     = (const float*)d_in[11];
    const float* out_w1 = (const float*)d_in[12];   // [128][128]
    const float* out_b1 = (const float*)d_in[13];
    const float* out_w2 = (const float*)d_in[14];   // [128][2]
    const float* out_b2 = (const float*)d_in[15];
    float* y = (float*)d_out;

    // ---- workspace carve (~208 MB) ----
    const size_t SZ_HLIT = (size_t)N_LIT * 64;
    const size_t SZ_HCLS = (size_t)N_CLS * 64;
    char* p = (char*)d_ws;
    auto take = [&](size_t bytes) -> char* {
        char* r = p; p += (bytes + 255) & ~(size_t)255; return r;
    };
    float*          h_lit      = (float*)take(SZ_HLIT * 4);
    unsigned short* h_cls      = (unsigned short*)take(SZ_HCLS * 2);
    unsigned short* X          = (unsigned short*)take(SZ_HLIT * 2);
    float*          inv_cls    = (float*)take((size_t)N_CLS * 4);
    float*          inv_lit    = (float*)take((size_t)N_LIT * 4);
    int*            row_ptr_cls= (int*)take((size_t)(N_CLS + 1) * 4);
    int*            row_ptr_lit= (int*)take((size_t)(N_LIT + 1) * 4);
    int*            lit_by_cls = (int*)take((size_t)NEDGE * 4);
    int*            cls_by_lit = (int*)take((size_t)NEDGE * 4);
    int*            bh         = (int*)take((size_t)NBLK_S * NBKT * 4);
    int*            off        = (int*)take((size_t)NBLK_S * NBKT * 4);
    int*            bktbase    = (int*)take((size_t)(NBKT + 1) * 4);
    size_t need = (size_t)(p - (char*)d_ws);

    // pair buffer aliases h_lit (dead until encoder): 19.2 MB <= 51.2 MB
    int2* tmp_pairs = (int2*)h_lit;

    dim3 B(256);

    if (ws_size < need) {
        float mb = (float)((double)ws_size / (1024.0 * 1024.0));
        diag_kernel<<<256, B, 0, stream>>>(y, out_size, mb);
        return;
    }

    // ---- CSR build (radix partition) ----
    csr_hist_kernel<<<NBLK_S, B, 0, stream>>>(edge_cls, 12, bh);
    csr_offsets_kernel<<<1, B, 0, stream>>>(bh, off, bktbase);
    csr_scatter_kernel<<<NBLK_S, B, 0, stream>>>(edge_cls, edge_lit, 12, off, tmp_pairs);
    csr_build_kernel<<<NBKT, B, 0, stream>>>(tmp_pairs, bktbase, 4096, N_CLS,
                                             row_ptr_cls, inv_cls, lit_by_cls);
    csr_hist_kernel<<<NBLK_S, B, 0, stream>>>(edge_lit, 10, bh);
    csr_offsets_kernel<<<1, B, 0, stream>>>(bh, off, bktbase);
    csr_scatter_kernel<<<NBLK_S, B, 0, stream>>>(edge_lit, edge_cls, 10, off, tmp_pairs);
    csr_build_kernel<<<NBKT, B, 0, stream>>>(tmp_pairs, bktbase, 1024, N_LIT,
                                             row_ptr_lit, inv_lit, cls_by_lit);
    tail_kernel<<<1, 64, 0, stream>>>(row_ptr_cls, row_ptr_lit);

    // ---- encoder (overwrites tmp_pairs alias region) ----
    encoder_kernel<<<2048, B, 0, stream>>>(x_lit, x_cls, enc_w1, enc_b1, enc_w2, enc_b2,
                                           h_lit, h_cls);

    // layer-0 X; layers 1..3 get X from lit_update's fused epilogue
    gemmX_kernel<<<1024, B, 0, stream>>>(h_lit, Wc + 64 * 64, X);

    for (int l = 0; l < 4; ++l) {
        const float* Wl_l = Wl + (size_t)l * 192 * 64;
        const float* Wc_next = (l < 3) ? (Wc + (size_t)(l + 1) * 128 * 64 + 64 * 64) : nullptr;
        cls_update_kernel<<<2048, B, 0, stream>>>(h_cls, X, row_ptr_cls, lit_by_cls,
                                                  inv_cls, Wc + (size_t)l * 128 * 64,
                                                  bc + l * 64);
        gather_lit_kernel<<<4096, B, 0, stream>>>(h_cls, row_ptr_lit, cls_by_lit,
                                                  inv_lit, X);
        lit_update_kernel<<<1024, B, 0, stream>>>(h_lit, X, Wl_l, bl + l * 64,
                                                  Wc_next, X);
    }

    // ---- readout ----
    var_hidden_kernel<<<4096, B, 0, stream>>>(h_lit, out_w1, out_b1, 0, X);
    var_hidden_kernel<<<4096, B, 0, stream>>>(h_lit, out_w1, out_b1, 64, X);
    out2_kernel<<<2048, B, 0, stream>>>(X, out_w2, out_b2, y);
}